// Round 11
// baseline (152.700 us; speedup 1.0000x reference)
//
#include <hip/hip_runtime.h>
#include <hip/hip_bf16.h>

#define CC 64
#define HW 9216
#define IMG 96
#define SPLITS 16
#define SPLEN 576             // 9216 / 16
#define ITERS 9               // 576 / 64
#define LOG2E 1.44269504f
#define RESC 5.545f           // defer-max headroom (nat-log); deferred p <= 2^8

typedef _Float16 f16;
typedef __attribute__((ext_vector_type(8))) _Float16 f16x8;
typedef __attribute__((ext_vector_type(4))) _Float16 f16x4;
typedef __attribute__((ext_vector_type(4))) float f32x4;
typedef __attribute__((ext_vector_type(16))) float f32x16;
typedef __attribute__((ext_vector_type(4))) unsigned int u32x4;

// ---------------- prepad + transpose: xt[p][ci] (p in 100x100 padded image, 64 f16 rows)
// 313 blocks of 32 positions; blocks >= 313: weight transform dW->dWt[tap][co][ci], cW->cWt
__global__ __launch_bounds__(256) void prepad_kernel(
    const float* __restrict__ x, const float* __restrict__ dW, const float* __restrict__ cW,
    f16* __restrict__ xt, f16* __restrict__ dWt, f16* __restrict__ cWt)
{
    __shared__ float tile[32][65];
    const int t = threadIdx.x;
    if (blockIdx.x >= 313) {
        const int wb = blockIdx.x - 313;          // 0..39, 40*1024 = 36864 + 4096
        #pragma unroll
        for (int j = 0; j < 4; ++j) {
            int idx = wb * 1024 + j * 256 + t;
            if (idx < 36864) {
                float val = dW[idx];
                int co = idx / 576;
                int r = idx - co * 576;
                int ci = r / 9, tap = r - ci * 9;
                dWt[tap * 4096 + co * 64 + ci] = (f16)val;
            } else {
                int c = idx - 36864;
                cWt[c] = (f16)cW[c];
            }
        }
        return;
    }
    const int p0 = blockIdx.x * 32;              // 313 image blocks
    const int pl = t & 31;
    const int p = p0 + pl;
    int r = p / 100, c = p % 100;
    bool interior = (r >= 2) && (r < 98) && (c >= 2) && (c < 98);
    int img = (r - 2) * IMG + (c - 2);
    #pragma unroll
    for (int j = 0; j < 8; ++j) {
        int ci = j * 8 + (t >> 5);
        tile[pl][ci] = interior ? x[ci * HW + img] : 0.f;
    }
    __syncthreads();
    const int row16 = t >> 4, chunk = t & 15;
    #pragma unroll
    for (int j = 0; j < 2; ++j) {
        int row = j * 16 + row16;                // 0..31
        int pr = p0 + row;
        if (pr < 10000) {
            f16x4 hv = {(f16)tile[row][chunk * 4 + 0], (f16)tile[row][chunk * 4 + 1],
                        (f16)tile[row][chunk * 4 + 2], (f16)tile[row][chunk * 4 + 3]};
            *(f16x4*)&xt[pr * 64 + chunk * 4] = hv;
        }
    }
}

// ---------------- MFMA conv: dilated 3x3 (9-tap GEMM over ci) + fused 1x1 (center tap)
// 1-wave blocks (2304 x 64): finer CU packing, no barriers, weights direct from L2.
__global__ __launch_bounds__(64) void conv_mfma_kernel(
    const f16* __restrict__ xt, const f16* __restrict__ dWt, const float* __restrict__ db,
    const f16* __restrict__ cWt, const float* __restrict__ cb,
    f16* __restrict__ yq, f16* __restrict__ kt, f16* __restrict__ vt)
{
    const int b = blockIdx.x;            // 576 pos-tiles * 4 co-groups
    const int tile = b >> 2, cog = b & 3;
    const int co0 = cog * 16;
    const int L = threadIdx.x;           // 0..63
    const int g = L >> 4, c16 = L & 15;

    f16x8 Bf[9][2], Bv[2];
    #pragma unroll
    for (int tap = 0; tap < 9; ++tap)
        #pragma unroll
        for (int kc = 0; kc < 2; ++kc)
            Bf[tap][kc] = *(const f16x8*)&dWt[(tap * 64 + co0 + c16) * 64 + g * 8 + kc * 32];
    #pragma unroll
    for (int kc = 0; kc < 2; ++kc)
        Bv[kc] = *(const f16x8*)&cWt[(co0 + c16) * 64 + g * 8 + kc * 32];

    const int ms = tile * 16;
    const int h = ms / IMG, wc = ms % IMG;
    const int pb = (h + 2) * 100 + (wc + 2) + c16;

    f32x4 accY = (f32x4){0.f, 0.f, 0.f, 0.f};
    f32x4 accV = (f32x4){0.f, 0.f, 0.f, 0.f};

    #pragma unroll
    for (int tap = 0; tap < 9; ++tap) {
        int kh = tap / 3, kw = tap % 3;
        int toff = (2 * kh - 2) * 100 + (2 * kw - 2);
        const f16* ap = xt + (pb + toff) * 64;
        f16x8 A0 = *(const f16x8*)(ap + g * 8);
        f16x8 A1 = *(const f16x8*)(ap + g * 8 + 32);
        accY = __builtin_amdgcn_mfma_f32_16x16x32_f16(A0, Bf[tap][0], accY, 0, 0, 0);
        accY = __builtin_amdgcn_mfma_f32_16x16x32_f16(A1, Bf[tap][1], accY, 0, 0, 0);
        if (tap == 4) {
            accV = __builtin_amdgcn_mfma_f32_16x16x32_f16(A0, Bv[0], accV, 0, 0, 0);
            accV = __builtin_amdgcn_mfma_f32_16x16x32_f16(A1, Bv[1], accV, 0, 0, 0);
        }
    }

    const float dbv = db[co0 + c16], cbv = cb[co0 + c16];
    f16 hy[4];
    #pragma unroll
    for (int j = 0; j < 4; ++j) hy[j] = (f16)(accY[j] + dbv);
    *(f16x4*)&yq[(co0 + c16) * HW + ms + 4 * g] = (f16x4){hy[0], hy[1], hy[2], hy[3]};
    #pragma unroll
    for (int j = 0; j < 4; ++j)
        kt[(ms + 4 * g + j) * 64 + co0 + c16] = hy[j];
    #pragma unroll
    for (int j = 0; j < 4; ++j) {
        int m = ms + 4 * g + j;
        vt[(m & 63) * HW + (co0 + c16) * 144 + (m >> 6)] = (f16)(accV[j] + cbv);
    }
}

// ---------------- MFMA flash attention, 32x32x16 tiles
// R8 core (uint4 staging between barriers, exp-first softmax, T13-lite defer),
// restructured to 2-wave / 64-query blocks: grid 2304 = exactly 9 blocks/CU
// (R8's 4-wave/1152-block config measured 25% occupancy — grid quantization).
__global__ __launch_bounds__(128, 4) void attn_kernel(
    const f16* __restrict__ kt, const f16* __restrict__ vt, const f16* __restrict__ yq,
    f16* __restrict__ acc_ws, float* __restrict__ m_ws, float* __restrict__ l_ws)
{
    __shared__ f16 sKT[64 * 64];        // [key_local][granule ^ (row&7)][8]
    __shared__ f16 sVT[64 * 64];        // [channel][granule ^ (row&7)][8]
    __shared__ float sAL[2 * 32];       // per-wave scale[query]

    const int t = threadIdx.x;          // 0..127
    const int L = t & 63, w = t >> 6;   // w in {0,1}
    const int l5 = L >> 5, l31 = L & 31;
    const int x7 = l31 & 7;
    const int qb = blockIdx.x >> 4, sp = blockIdx.x & (SPLITS - 1);
    const int n0 = qb * 64;             // 144 query-blocks of 64
    const int mbase = sp * SPLEN;
    float* alw = (float*)sAL + w * 32;

    // staging: 128 threads cover rows 0..15 (+16*rep), 8 chunks each
    const int srow = t >> 3, sch = t & 7;

    // Q B-fragments (query = n0 + 32w + l31, ci chunks of 16) — raw-reshape q, faithful
    f16x8 qf[4];
    #pragma unroll
    for (int kc = 0; kc < 4; ++kc)
        qf[kc] = *(const f16x8*)(yq + (n0 + w * 32 + l31) * 64 + kc * 16 + l5 * 8);

    float mi = -1e30f, mtrue = -1e30f, li = 0.f;    // mi = exp reference, mtrue = true max
    f32x16 acc[2];
    #pragma unroll
    for (int ct = 0; ct < 2; ++ct)
        #pragma unroll
        for (int r = 0; r < 16; ++r) acc[ct][r] = 0.f;

    for (int it = 0; it < ITERS; ++it) {
        const int m0 = mbase + it * 64;
        __syncthreads();
        #pragma unroll
        for (int rep = 0; rep < 4; ++rep) {
            int row = srow + rep * 16;
            int dst = row * 64 + ((sch ^ (row & 7)) << 3);
            *(uint4*)&sKT[dst] = *(const uint4*)&kt[(m0 + row) * 64 + sch * 8];
            *(uint4*)&sVT[dst] = *(const uint4*)&vt[row * HW + m0 + sch * 8];
        }
        __syncthreads();

        // S^T: D[key32-tile][query]; lane: query=l31, keys kt2*32 + 8*(r>>2) + 4*l5 + (r&3)
        f32x16 st[2];
        #pragma unroll
        for (int kt2 = 0; kt2 < 2; ++kt2) {
            f32x16 d;
            #pragma unroll
            for (int r = 0; r < 16; ++r) d[r] = 0.f;
            #pragma unroll
            for (int kc = 0; kc < 4; ++kc) {
                f16x8 af = *(const f16x8*)&sKT[(kt2 * 32 + l31) * 64 + ((((kc << 1) | l5) ^ x7) << 3)];
                d = __builtin_amdgcn_mfma_f32_32x32x16_f16(af, qf[kc], d, 0, 0, 0);
            }
            st[kt2] = d;
        }
        // threshold mask to ZERO
        #pragma unroll
        for (int kt2 = 0; kt2 < 2; ++kt2)
            #pragma unroll
            for (int r = 0; r < 16; ++r)
                st[kt2][r] = (fabsf(st[kt2][r]) > 0.3f) ? st[kt2][r] : 0.f;

        // row max: local tree + 1 shfl (partner l5 holds other half of this query's keys)
        float q8[8];
        #pragma unroll
        for (int kt2 = 0; kt2 < 2; ++kt2)
            #pragma unroll
            for (int rq = 0; rq < 4; ++rq)
                q8[kt2 * 4 + rq] = fmaxf(fmaxf(st[kt2][rq * 4 + 0], st[kt2][rq * 4 + 1]),
                                         fmaxf(st[kt2][rq * 4 + 2], st[kt2][rq * 4 + 3]));
        float mx = fmaxf(fmaxf(fmaxf(q8[0], q8[1]), fmaxf(q8[2], q8[3])),
                         fmaxf(fmaxf(q8[4], q8[5]), fmaxf(q8[6], q8[7])));
        mx = fmaxf(mx, __shfl_xor(mx, 32, 64));
        mtrue = fmaxf(mtrue, mx);

        // T13-lite: only change the reference when it grows past the headroom
        unsigned long long need = __ballot(mx > mi + RESC);   // wave-uniform
        float mnew = need ? fmaxf(mi, mx) : mi;
        float nL = mnew * LOG2E;
        float alpha = __builtin_amdgcn_exp2f(mi * LOG2E - nL);   // == 1 when deferred

        // p = exp2(s*L2E - nL) (bounded by 2^8); pack to f16 pairs; partial sum ls
        // (st dies here — BEFORE the acc-rescale; keeps peak VGPR low, no spill)
        float ls = 0.f;
        unsigned int u[2][4][2];
        #pragma unroll
        for (int kt2 = 0; kt2 < 2; ++kt2)
            #pragma unroll
            for (int rq = 0; rq < 4; ++rq) {
                float p0 = __builtin_amdgcn_exp2f(fmaf(st[kt2][rq * 4 + 0], LOG2E, -nL));
                float p1 = __builtin_amdgcn_exp2f(fmaf(st[kt2][rq * 4 + 1], LOG2E, -nL));
                float p2 = __builtin_amdgcn_exp2f(fmaf(st[kt2][rq * 4 + 2], LOG2E, -nL));
                float p3 = __builtin_amdgcn_exp2f(fmaf(st[kt2][rq * 4 + 3], LOG2E, -nL));
                ls += (p0 + p1) + (p2 + p3);
                u[kt2][rq][0] = __builtin_bit_cast(unsigned int, __builtin_amdgcn_cvt_pkrtz(p0, p1));
                u[kt2][rq][1] = __builtin_bit_cast(unsigned int, __builtin_amdgcn_cvt_pkrtz(p2, p3));
            }

        if (need) {
            li = li * alpha + ls;
            if (l5 == 0) alw[l31] = alpha;
            f32x4 aj[4];
            #pragma unroll
            for (int rq = 0; rq < 4; ++rq)
                aj[rq] = *(const f32x4*)&alw[rq * 8 + l5 * 4];
            #pragma unroll
            for (int ct = 0; ct < 2; ++ct)
                #pragma unroll
                for (int r = 0; r < 16; ++r)
                    acc[ct][r] *= aj[r >> 2][r & 3];
        } else {
            li += ls;                    // alpha == 1 for every lane
        }
        mi = mnew;

        // PV: A-fragments assembled in-register.
        // Consumer lane (l5,l31) for chunk kc needs keys kc*16 + l5*8 + {0..7}
        //   = kt2*32 + rq*8 + {0..7} with kt2 = kc>>1, rq = (kc&1)*2 + l5 (consumer l5!).
        // swap(a,b): ret[0] = {a.lo, b.lo}, ret[1] = {a.hi, b.hi}
        //   a = u[kt2][rq0] (for l5=0 consumers), b = u[kt2][rq1] (for l5=1):
        //   w0 = ret[0] i=0, w1 = ret[0] i=1, w2 = ret[1] i=0, w3 = ret[1] i=1.
        #pragma unroll
        for (int kc = 0; kc < 4; ++kc) {
            const int kt2 = kc >> 1;
            const int rq0 = (kc & 1) * 2, rq1 = rq0 + 1;
            auto rA = __builtin_amdgcn_permlane32_swap(
                (int)u[kt2][rq0][0], (int)u[kt2][rq1][0], false, false);
            auto rB = __builtin_amdgcn_permlane32_swap(
                (int)u[kt2][rq0][1], (int)u[kt2][rq1][1], false, false);
            u32x4 pw = {(unsigned int)rA[0], (unsigned int)rB[0],
                        (unsigned int)rA[1], (unsigned int)rB[1]};   // w0,w1,w2,w3
            f16x8 pa = __builtin_bit_cast(f16x8, pw);
            #pragma unroll
            for (int ct = 0; ct < 2; ++ct) {
                int vrow = ct * 32 + l31;
                f16x8 vb = *(const f16x8*)&sVT[vrow * 64 + ((((kc << 1) | l5) ^ x7) << 3)];
                acc[ct] = __builtin_amdgcn_mfma_f32_32x32x16_f16(pa, vb, acc[ct], 0, 0, 0);
            }
        }
    }

    // T13 final rescale to true-max units (keeps f16 partials in range; post-loop)
    float fsc = __builtin_amdgcn_exp2f((mi - mtrue) * LOG2E);
    li *= fsc;
    float li_tot = li + __shfl_xor(li, 32, 64);
    if (l5 == 0) alw[l31] = fsc;
    f32x4 fj[4];
    #pragma unroll
    for (int rq = 0; rq < 4; ++rq)
        fj[rq] = *(const f32x4*)&alw[rq * 8 + l5 * 4];
    #pragma unroll
    for (int ct = 0; ct < 2; ++ct)
        #pragma unroll
        for (int r = 0; r < 16; ++r)
            acc[ct][r] *= fj[r >> 2][r & 3];

    // write partials: acc_ws[base*4096 + q_local*64 + c], q_local in 0..63
    const int base = blockIdx.x;
    #pragma unroll
    for (int ct = 0; ct < 2; ++ct)
        #pragma unroll
        for (int r = 0; r < 16; ++r) {
            int ql = w * 32 + (r & 3) + 8 * (r >> 2) + 4 * l5;
            int c  = ct * 32 + l31;
            acc_ws[base * 4096 + ql * 64 + c] = (f16)acc[ct][r];
        }
    if (l5 == 0) {
        m_ws[base * 64 + w * 32 + l31] = mtrue;    // true max (unscaled units)
        l_ws[base * 64 + w * 32 + l31] = li_tot;
    }
}

// ---------------- merge splits + residual + transpose; grid 576 (16-row tiles, 64-q blocks)
// Vectorized: f16x4 partial reads (one pass, 256B/wave) + float4 residual writes.
__global__ __launch_bounds__(256) void merge_kernel(
    const f16* __restrict__ acc_ws, const float* __restrict__ m_ws, const float* __restrict__ l_ws,
    const float* __restrict__ x, float* __restrict__ out)
{
    __shared__ float wsh[SPLITS * 16];
    __shared__ float att[64 * 17];
    const int b = blockIdx.x;            // 576 tiles of 16 query rows
    const int row0 = b * 16;
    const int qb = row0 >> 6;            // 16-row tile never crosses a 64-q block
    const int ql0 = row0 & 63;
    const int t = threadIdx.x;
    if (t < 16) {
        int ql = ql0 + t;
        float ms = -1e30f;
        float mv[SPLITS];
        #pragma unroll
        for (int sp = 0; sp < SPLITS; ++sp) {
            mv[sp] = m_ws[(qb * SPLITS + sp) * 64 + ql];
            ms = fmaxf(ms, mv[sp]);
        }
        float Lsum = 0.f, ev[SPLITS];
        #pragma unroll
        for (int sp = 0; sp < SPLITS; ++sp) {
            ev[sp] = __builtin_amdgcn_exp2f((mv[sp] - ms) * LOG2E);
            Lsum += l_ws[(qb * SPLITS + sp) * 64 + ql] * ev[sp];
        }
        float inv = 1.f / Lsum;
        #pragma unroll
        for (int sp = 0; sp < SPLITS; ++sp)
            wsh[sp * 16 + t] = ev[sp] * inv;
    }
    __syncthreads();
    {
        // thread t: rr = t>>4 (query row), c0 = (t&15)*4 (4 channels) — 16 thr x 16B = 256B
        const int rr = t >> 4, c0 = (t & 15) * 4;
        float v0 = 0.f, v1 = 0.f, v2 = 0.f, v3 = 0.f;
        #pragma unroll
        for (int sp = 0; sp < SPLITS; ++sp) {
            f16x4 hv = *(const f16x4*)&acc_ws[(qb * SPLITS + sp) * 4096 + (ql0 + rr) * 64 + c0];
            float wv = wsh[sp * 16 + rr];
            v0 += (float)hv[0] * wv;
            v1 += (float)hv[1] * wv;
            v2 += (float)hv[2] * wv;
            v3 += (float)hv[3] * wv;
        }
        att[(c0 + 0) * 17 + rr] = v0;
        att[(c0 + 1) * 17 + rr] = v1;
        att[(c0 + 2) * 17 + rr] = v2;
        att[(c0 + 3) * 17 + rr] = v3;
    }
    __syncthreads();
    {
        // thread t: c = t>>2 (channel), r0 = (t&3)*4 — float4 fully coalesced
        const int c = t >> 2, r0 = (t & 3) * 4;
        const int idx = c * HW + row0 + r0;
        float4 xv = *(const float4*)&x[idx];
        float4 ov;
        ov.x = xv.x + att[c * 17 + r0 + 0];
        ov.y = xv.y + att[c * 17 + r0 + 1];
        ov.z = xv.z + att[c * 17 + r0 + 2];
        ov.w = xv.w + att[c * 17 + r0 + 3];
        *(float4*)&out[idx] = ov;
    }
}

extern "C" void kernel_launch(void* const* d_in, const int* in_sizes, int n_in,
                              void* d_out, int out_size, void* d_ws, size_t ws_size,
                              hipStream_t stream)
{
    const float* x  = (const float*)d_in[0];
    const float* dW = (const float*)d_in[1];
    const float* db = (const float*)d_in[2];
    const float* cW = (const float*)d_in[3];
    const float* cb = (const float*)d_in[4];
    float* out = (float*)d_out;

    char* ws = (char*)d_ws;
    f16* kt     = (f16*)(ws);                        //  1,179,648 B
    f16* yq     = (f16*)(ws + 1179648);              //  1,179,648 B
    f16* vt     = (f16*)(ws + 2359296);              //  1,179,648 B
    f16* xt     = (f16*)(ws + 3538944);              //  1,280,000 B (xt[p][ci])
    f16* dWt    = (f16*)(ws + 4818944);              //     73,728 B [tap][co][ci]
    f16* cWt    = (f16*)(ws + 4892672);              //      8,192 B [co][ci]
    f16* acc_ws = (f16*)(ws + 4900864);              // 18,874,368 B (2304 blk * 4096)
    float* m_ws = (float*)(ws + 23775232);           //    589,824 B (2304 * 64)
    float* l_ws = (float*)(ws + 24365056);           //    589,824 B
                                                     // total 24,954,880 B

    prepad_kernel<<<dim3(353), dim3(256), 0, stream>>>(x, dW, cW, xt, dWt, cWt);
    conv_mfma_kernel<<<dim3(2304), dim3(64), 0, stream>>>(xt, dWt, db, cWt, cb, yq, kt, vt);
    attn_kernel<<<dim3(144 * SPLITS), dim3(128), 0, stream>>>(kt, vt, yq, acc_ws, m_ws, l_ws);
    merge_kernel<<<dim3(576), dim3(256), 0, stream>>>(acc_ws, m_ws, l_ws, x, out);
}

// Round 12
// 128.375 us; speedup vs baseline: 1.1895x; 1.1895x over previous
//
#include <hip/hip_runtime.h>
#include <hip/hip_bf16.h>

#define CC 64
#define HW 9216
#define IMG 96
#define SPLITS 16
#define SPLEN 576             // 9216 / 16
#define ITERS 9               // 576 / 64
#define LOG2E 1.44269504f
#define RESC 5.545f           // defer-max headroom (nat-log); deferred p <= 2^8

typedef _Float16 f16;
typedef __attribute__((ext_vector_type(8))) _Float16 f16x8;
typedef __attribute__((ext_vector_type(4))) _Float16 f16x4;
typedef __attribute__((ext_vector_type(4))) float f32x4;
typedef __attribute__((ext_vector_type(16))) float f32x16;
typedef __attribute__((ext_vector_type(4))) unsigned int u32x4;

// ---------------- prepad + transpose: xt[p][ci] (p in 100x100 padded image, 64 f16 rows)
// 313 blocks of 32 positions; blocks >= 313: weight transform dW->dWt[tap][co][ci], cW->cWt
__global__ __launch_bounds__(256) void prepad_kernel(
    const float* __restrict__ x, const float* __restrict__ dW, const float* __restrict__ cW,
    f16* __restrict__ xt, f16* __restrict__ dWt, f16* __restrict__ cWt)
{
    __shared__ float tile[32][65];
    const int t = threadIdx.x;
    if (blockIdx.x >= 313) {
        const int wb = blockIdx.x - 313;          // 0..39, 40*1024 = 36864 + 4096
        #pragma unroll
        for (int j = 0; j < 4; ++j) {
            int idx = wb * 1024 + j * 256 + t;
            if (idx < 36864) {
                float val = dW[idx];
                int co = idx / 576;
                int r = idx - co * 576;
                int ci = r / 9, tap = r - ci * 9;
                dWt[tap * 4096 + co * 64 + ci] = (f16)val;
            } else {
                int c = idx - 36864;
                cWt[c] = (f16)cW[c];
            }
        }
        return;
    }
    const int p0 = blockIdx.x * 32;              // 313 image blocks
    const int pl = t & 31;
    const int p = p0 + pl;
    int r = p / 100, c = p % 100;
    bool interior = (r >= 2) && (r < 98) && (c >= 2) && (c < 98);
    int img = (r - 2) * IMG + (c - 2);
    #pragma unroll
    for (int j = 0; j < 8; ++j) {
        int ci = j * 8 + (t >> 5);
        tile[pl][ci] = interior ? x[ci * HW + img] : 0.f;
    }
    __syncthreads();
    const int row16 = t >> 4, chunk = t & 15;
    #pragma unroll
    for (int j = 0; j < 2; ++j) {
        int row = j * 16 + row16;                // 0..31
        int pr = p0 + row;
        if (pr < 10000) {
            f16x4 hv = {(f16)tile[row][chunk * 4 + 0], (f16)tile[row][chunk * 4 + 1],
                        (f16)tile[row][chunk * 4 + 2], (f16)tile[row][chunk * 4 + 3]};
            *(f16x4*)&xt[pr * 64 + chunk * 4] = hv;
        }
    }
}

// ---------------- MFMA conv: dilated 3x3 (9-tap GEMM over ci) + fused 1x1 (center tap)
// 1-wave blocks (2304 x 64): finer CU packing, no barriers, weights direct from L2.
__global__ __launch_bounds__(64) void conv_mfma_kernel(
    const f16* __restrict__ xt, const f16* __restrict__ dWt, const float* __restrict__ db,
    const f16* __restrict__ cWt, const float* __restrict__ cb,
    f16* __restrict__ yq, f16* __restrict__ kt, f16* __restrict__ vt)
{
    const int b = blockIdx.x;            // 576 pos-tiles * 4 co-groups
    const int tile = b >> 2, cog = b & 3;
    const int co0 = cog * 16;
    const int L = threadIdx.x;           // 0..63
    const int g = L >> 4, c16 = L & 15;

    f16x8 Bf[9][2], Bv[2];
    #pragma unroll
    for (int tap = 0; tap < 9; ++tap)
        #pragma unroll
        for (int kc = 0; kc < 2; ++kc)
            Bf[tap][kc] = *(const f16x8*)&dWt[(tap * 64 + co0 + c16) * 64 + g * 8 + kc * 32];
    #pragma unroll
    for (int kc = 0; kc < 2; ++kc)
        Bv[kc] = *(const f16x8*)&cWt[(co0 + c16) * 64 + g * 8 + kc * 32];

    const int ms = tile * 16;
    const int h = ms / IMG, wc = ms % IMG;
    const int pb = (h + 2) * 100 + (wc + 2) + c16;

    f32x4 accY = (f32x4){0.f, 0.f, 0.f, 0.f};
    f32x4 accV = (f32x4){0.f, 0.f, 0.f, 0.f};

    #pragma unroll
    for (int tap = 0; tap < 9; ++tap) {
        int kh = tap / 3, kw = tap % 3;
        int toff = (2 * kh - 2) * 100 + (2 * kw - 2);
        const f16* ap = xt + (pb + toff) * 64;
        f16x8 A0 = *(const f16x8*)(ap + g * 8);
        f16x8 A1 = *(const f16x8*)(ap + g * 8 + 32);
        accY = __builtin_amdgcn_mfma_f32_16x16x32_f16(A0, Bf[tap][0], accY, 0, 0, 0);
        accY = __builtin_amdgcn_mfma_f32_16x16x32_f16(A1, Bf[tap][1], accY, 0, 0, 0);
        if (tap == 4) {
            accV = __builtin_amdgcn_mfma_f32_16x16x32_f16(A0, Bv[0], accV, 0, 0, 0);
            accV = __builtin_amdgcn_mfma_f32_16x16x32_f16(A1, Bv[1], accV, 0, 0, 0);
        }
    }

    const float dbv = db[co0 + c16], cbv = cb[co0 + c16];
    f16 hy[4];
    #pragma unroll
    for (int j = 0; j < 4; ++j) hy[j] = (f16)(accY[j] + dbv);
    *(f16x4*)&yq[(co0 + c16) * HW + ms + 4 * g] = (f16x4){hy[0], hy[1], hy[2], hy[3]};
    #pragma unroll
    for (int j = 0; j < 4; ++j)
        kt[(ms + 4 * g + j) * 64 + co0 + c16] = hy[j];
    #pragma unroll
    for (int j = 0; j < 4; ++j) {
        int m = ms + 4 * g + j;
        vt[(m & 63) * HW + (co0 + c16) * 144 + (m >> 6)] = (f16)(accV[j] + cbv);
    }
}

// ---------------- MFMA flash attention, 32x32x16 tiles — R8 structure verbatim
// (uint4 staging between barriers, single-buffer LDS, exp/pack BEFORE the acc-rescale
// branch so st[] dies first: fits 64 VGPRs, zero scratch traffic — verified R8).
// T13-lite deferred rescale; alpha exp2 hoisted inside the need-branch.
__global__ __launch_bounds__(256, 4) void attn_kernel(
    const f16* __restrict__ kt, const f16* __restrict__ vt, const f16* __restrict__ yq,
    f16* __restrict__ acc_ws, float* __restrict__ m_ws, float* __restrict__ l_ws)
{
    __shared__ f16 sKT[64 * 64];        // [key_local][granule ^ (row&7)][8]
    __shared__ f16 sVT[64 * 64];        // [channel][granule ^ (row&7)][8]
    __shared__ float sAL[4 * 32];       // per-wave scale[query]

    const int t = threadIdx.x;
    const int L = t & 63, w = t >> 6;
    const int l5 = L >> 5, l31 = L & 31;
    const int x7 = l31 & 7;
    const int qb = blockIdx.x >> 4, sp = blockIdx.x & (SPLITS - 1);
    const int n0 = qb * 128;
    const int mbase = sp * SPLEN;
    float* alw = (float*)sAL + w * 32;

    // staging addresses (per-thread constant parts)
    const int srow0 = t >> 3, sch = t & 7;          // rep 0: rows 0..31
    const int srow1 = srow0 + 32;                   // rep 1: rows 32..63
    const int dst0 = srow0 * 64 + ((sch ^ (srow0 & 7)) << 3);
    const int dst1 = srow1 * 64 + ((sch ^ (srow1 & 7)) << 3);

    // Q B-fragments (query = n0 + 32w + l31, ci chunks of 16) — raw-reshape q, faithful
    f16x8 qf[4];
    #pragma unroll
    for (int kc = 0; kc < 4; ++kc)
        qf[kc] = *(const f16x8*)(yq + (n0 + w * 32 + l31) * 64 + kc * 16 + l5 * 8);

    float mi = -1e30f, mtrue = -1e30f, li = 0.f;    // mi = exp reference, mtrue = true max
    f32x16 acc[2];
    #pragma unroll
    for (int ct = 0; ct < 2; ++ct)
        #pragma unroll
        for (int r = 0; r < 16; ++r) acc[ct][r] = 0.f;

    for (int it = 0; it < ITERS; ++it) {
        const int m0 = mbase + it * 64;
        __syncthreads();
        *(uint4*)&sKT[dst0] = *(const uint4*)&kt[(m0 + srow0) * 64 + sch * 8];
        *(uint4*)&sKT[dst1] = *(const uint4*)&kt[(m0 + srow1) * 64 + sch * 8];
        *(uint4*)&sVT[dst0] = *(const uint4*)&vt[srow0 * HW + m0 + sch * 8];
        *(uint4*)&sVT[dst1] = *(const uint4*)&vt[srow1 * HW + m0 + sch * 8];
        __syncthreads();

        // S^T: D[key32-tile][query]; lane: query=l31, keys kt2*32 + 8*(r>>2) + 4*l5 + (r&3)
        f32x16 st[2];
        #pragma unroll
        for (int kt2 = 0; kt2 < 2; ++kt2) {
            f32x16 d;
            #pragma unroll
            for (int r = 0; r < 16; ++r) d[r] = 0.f;
            #pragma unroll
            for (int kc = 0; kc < 4; ++kc) {
                f16x8 af = *(const f16x8*)&sKT[(kt2 * 32 + l31) * 64 + ((((kc << 1) | l5) ^ x7) << 3)];
                d = __builtin_amdgcn_mfma_f32_32x32x16_f16(af, qf[kc], d, 0, 0, 0);
            }
            st[kt2] = d;
        }
        // threshold mask to ZERO
        #pragma unroll
        for (int kt2 = 0; kt2 < 2; ++kt2)
            #pragma unroll
            for (int r = 0; r < 16; ++r)
                st[kt2][r] = (fabsf(st[kt2][r]) > 0.3f) ? st[kt2][r] : 0.f;

        // row max: local tree + 1 shfl (partner l5 holds other half of this query's keys)
        float q8[8];
        #pragma unroll
        for (int kt2 = 0; kt2 < 2; ++kt2)
            #pragma unroll
            for (int rq = 0; rq < 4; ++rq)
                q8[kt2 * 4 + rq] = fmaxf(fmaxf(st[kt2][rq * 4 + 0], st[kt2][rq * 4 + 1]),
                                         fmaxf(st[kt2][rq * 4 + 2], st[kt2][rq * 4 + 3]));
        float mx = fmaxf(fmaxf(fmaxf(q8[0], q8[1]), fmaxf(q8[2], q8[3])),
                         fmaxf(fmaxf(q8[4], q8[5]), fmaxf(q8[6], q8[7])));
        mx = fmaxf(mx, __shfl_xor(mx, 32, 64));
        mtrue = fmaxf(mtrue, mx);

        // T13-lite: only change the reference when it grows past the headroom
        unsigned long long need = __ballot(mx > mi + RESC);   // wave-uniform
        float mnew = need ? fmaxf(mi, mx) : mi;
        float nL = mnew * LOG2E;

        // p = exp2(s*L2E - nL) (bounded by 2^8); pack to f16 pairs; partial sum ls
        // (st dies here — BEFORE the acc-rescale; keeps peak VGPR <= 64)
        float ls = 0.f;
        unsigned int u[2][4][2];
        #pragma unroll
        for (int kt2 = 0; kt2 < 2; ++kt2)
            #pragma unroll
            for (int rq = 0; rq < 4; ++rq) {
                float p0 = __builtin_amdgcn_exp2f(fmaf(st[kt2][rq * 4 + 0], LOG2E, -nL));
                float p1 = __builtin_amdgcn_exp2f(fmaf(st[kt2][rq * 4 + 1], LOG2E, -nL));
                float p2 = __builtin_amdgcn_exp2f(fmaf(st[kt2][rq * 4 + 2], LOG2E, -nL));
                float p3 = __builtin_amdgcn_exp2f(fmaf(st[kt2][rq * 4 + 3], LOG2E, -nL));
                ls += (p0 + p1) + (p2 + p3);
                u[kt2][rq][0] = __builtin_bit_cast(unsigned int, __builtin_amdgcn_cvt_pkrtz(p0, p1));
                u[kt2][rq][1] = __builtin_bit_cast(unsigned int, __builtin_amdgcn_cvt_pkrtz(p2, p3));
            }

        if (need) {
            float alpha = __builtin_amdgcn_exp2f(mi * LOG2E - nL);
            li = li * alpha + ls;
            if (l5 == 0) alw[l31] = alpha;
            f32x4 aj[4];
            #pragma unroll
            for (int rq = 0; rq < 4; ++rq)
                aj[rq] = *(const f32x4*)&alw[rq * 8 + l5 * 4];
            #pragma unroll
            for (int ct = 0; ct < 2; ++ct)
                #pragma unroll
                for (int r = 0; r < 16; ++r)
                    acc[ct][r] *= aj[r >> 2][r & 3];
        } else {
            li += ls;                    // alpha == 1 for every lane
        }
        mi = mnew;

        // PV: A-fragments assembled in-register.
        // Consumer lane (l5,l31) for chunk kc needs keys kc*16 + l5*8 + {0..7}
        //   = kt2*32 + rq*8 + {0..7} with kt2 = kc>>1, rq = (kc&1)*2 + l5 (consumer l5!).
        // swap(a,b): ret[0] = {a.lo, b.lo}, ret[1] = {a.hi, b.hi}
        //   a = u[kt2][rq0] (for l5=0 consumers), b = u[kt2][rq1] (for l5=1):
        //   w0 = ret[0] i=0, w1 = ret[0] i=1, w2 = ret[1] i=0, w3 = ret[1] i=1.
        #pragma unroll
        for (int kc = 0; kc < 4; ++kc) {
            const int kt2 = kc >> 1;
            const int rq0 = (kc & 1) * 2, rq1 = rq0 + 1;
            auto rA = __builtin_amdgcn_permlane32_swap(
                (int)u[kt2][rq0][0], (int)u[kt2][rq1][0], false, false);
            auto rB = __builtin_amdgcn_permlane32_swap(
                (int)u[kt2][rq0][1], (int)u[kt2][rq1][1], false, false);
            u32x4 pw = {(unsigned int)rA[0], (unsigned int)rB[0],
                        (unsigned int)rA[1], (unsigned int)rB[1]};   // w0,w1,w2,w3
            f16x8 pa = __builtin_bit_cast(f16x8, pw);
            #pragma unroll
            for (int ct = 0; ct < 2; ++ct) {
                int vrow = ct * 32 + l31;
                f16x8 vb = *(const f16x8*)&sVT[vrow * 64 + ((((kc << 1) | l5) ^ x7) << 3)];
                acc[ct] = __builtin_amdgcn_mfma_f32_32x32x16_f16(pa, vb, acc[ct], 0, 0, 0);
            }
        }
    }

    // T13 final rescale to true-max units (keeps f16 partials in range; post-loop)
    float fsc = __builtin_amdgcn_exp2f((mi - mtrue) * LOG2E);
    li *= fsc;
    float li_tot = li + __shfl_xor(li, 32, 64);
    if (l5 == 0) alw[l31] = fsc;
    f32x4 fj[4];
    #pragma unroll
    for (int rq = 0; rq < 4; ++rq)
        fj[rq] = *(const f32x4*)&alw[rq * 8 + l5 * 4];
    #pragma unroll
    for (int ct = 0; ct < 2; ++ct)
        #pragma unroll
        for (int r = 0; r < 16; ++r)
            acc[ct][r] *= fj[r >> 2][r & 3];

    // write partials: acc_ws[base*8192 + q_local*64 + c]
    const int base = blockIdx.x;
    #pragma unroll
    for (int ct = 0; ct < 2; ++ct)
        #pragma unroll
        for (int r = 0; r < 16; ++r) {
            int ql = w * 32 + (r & 3) + 8 * (r >> 2) + 4 * l5;
            int c  = ct * 32 + l31;
            acc_ws[base * 8192 + ql * 64 + c] = (f16)acc[ct][r];
        }
    if (l5 == 0) {
        m_ws[base * 128 + w * 32 + l31] = mtrue;   // true max (unscaled units)
        l_ws[base * 128 + w * 32 + l31] = li_tot;
    }
}

// ---------------- merge splits + residual + transpose
// 8-row tiles, 128 threads, grid 1152: 2x the resident blocks/CU of the 16-row
// version for the 18.9 MB partial-read phase (merge is BW/latency-bound).
__global__ __launch_bounds__(128) void merge_kernel(
    const f16* __restrict__ acc_ws, const float* __restrict__ m_ws, const float* __restrict__ l_ws,
    const float* __restrict__ x, float* __restrict__ out)
{
    __shared__ float wsh[SPLITS * 8];
    __shared__ float att[64 * 9];
    const int b = blockIdx.x;            // 1152 tiles of 8 query rows
    const int row0 = b * 8;
    const int qb = row0 >> 7;            // 8-row tile never crosses a 128-q block
    const int ql0 = row0 & 127;
    const int t = threadIdx.x;           // 0..127
    if (t < 8) {
        int ql = ql0 + t;
        float ms = -1e30f;
        float mv[SPLITS];
        #pragma unroll
        for (int sp = 0; sp < SPLITS; ++sp) {
            mv[sp] = m_ws[(qb * SPLITS + sp) * 128 + ql];
            ms = fmaxf(ms, mv[sp]);
        }
        float Lsum = 0.f, ev[SPLITS];
        #pragma unroll
        for (int sp = 0; sp < SPLITS; ++sp) {
            ev[sp] = __builtin_amdgcn_exp2f((mv[sp] - ms) * LOG2E);
            Lsum += l_ws[(qb * SPLITS + sp) * 128 + ql] * ev[sp];
        }
        float inv = 1.f / Lsum;
        #pragma unroll
        for (int sp = 0; sp < SPLITS; ++sp)
            wsh[sp * 8 + t] = ev[sp] * inv;
    }
    __syncthreads();
    {
        // thread t: rr = t>>4 (query row 0..7), c0 = (t&15)*4 — 16 thr x 16B = 256B/row
        const int rr = t >> 4, c0 = (t & 15) * 4;
        const int qlr = ql0 + rr;
        float v0 = 0.f, v1 = 0.f, v2 = 0.f, v3 = 0.f;
        #pragma unroll
        for (int sp = 0; sp < SPLITS; ++sp) {
            f16x4 hv = *(const f16x4*)&acc_ws[(qb * SPLITS + sp) * 8192 + qlr * 64 + c0];
            float wv = wsh[sp * 8 + rr];
            v0 += (float)hv[0] * wv;
            v1 += (float)hv[1] * wv;
            v2 += (float)hv[2] * wv;
            v3 += (float)hv[3] * wv;
        }
        att[(c0 + 0) * 9 + rr] = v0;
        att[(c0 + 1) * 9 + rr] = v1;
        att[(c0 + 2) * 9 + rr] = v2;
        att[(c0 + 3) * 9 + rr] = v3;
    }
    __syncthreads();
    {
        // thread t: c = t>>1 (channel), r0 = (t&1)*4 — float4 writes
        const int c = t >> 1, r0 = (t & 1) * 4;
        const int idx = c * HW + row0 + r0;
        float4 xv = *(const float4*)&x[idx];
        float4 ov;
        ov.x = xv.x + att[c * 9 + r0 + 0];
        ov.y = xv.y + att[c * 9 + r0 + 1];
        ov.z = xv.z + att[c * 9 + r0 + 2];
        ov.w = xv.w + att[c * 9 + r0 + 3];
        *(float4*)&out[idx] = ov;
    }
}

extern "C" void kernel_launch(void* const* d_in, const int* in_sizes, int n_in,
                              void* d_out, int out_size, void* d_ws, size_t ws_size,
                              hipStream_t stream)
{
    const float* x  = (const float*)d_in[0];
    const float* dW = (const float*)d_in[1];
    const float* db = (const float*)d_in[2];
    const float* cW = (const float*)d_in[3];
    const float* cb = (const float*)d_in[4];
    float* out = (float*)d_out;

    char* ws = (char*)d_ws;
    f16* kt     = (f16*)(ws);                        //  1,179,648 B
    f16* yq     = (f16*)(ws + 1179648);              //  1,179,648 B
    f16* vt     = (f16*)(ws + 2359296);              //  1,179,648 B
    f16* xt     = (f16*)(ws + 3538944);              //  1,280,000 B (xt[p][ci])
    f16* dWt    = (f16*)(ws + 4818944);              //     73,728 B [tap][co][ci]
    f16* cWt    = (f16*)(ws + 4892672);              //      8,192 B [co][ci]
    f16* acc_ws = (f16*)(ws + 4900864);              // 18,874,368 B (1152 blk * 8192)
    float* m_ws = (float*)(ws + 23775232);           //    589,824 B (1152 * 128)
    float* l_ws = (float*)(ws + 24365056);           //    589,824 B
                                                     // total 24,954,880 B

    prepad_kernel<<<dim3(353), dim3(256), 0, stream>>>(x, dW, cW, xt, dWt, cWt);
    conv_mfma_kernel<<<dim3(2304), dim3(64), 0, stream>>>(xt, dWt, db, cWt, cb, yq, kt, vt);
    attn_kernel<<<dim3(72 * SPLITS), dim3(256), 0, stream>>>(kt, vt, yq, acc_ws, m_ws, l_ws);
    merge_kernel<<<dim3(1152), dim3(128), 0, stream>>>(acc_ws, m_ws, l_ws, x, out);
}